// Round 19
// baseline (527.286 us; speedup 1.0000x reference)
//
#include <hip/hip_runtime.h>
#include <hip/hip_bf16.h>

typedef short bf8 __attribute__((ext_vector_type(8)));   // 8 bf16 (4 VGPRs)
typedef short bf4 __attribute__((ext_vector_type(4)));   // 4 bf16 (8 B)
typedef float f4 __attribute__((ext_vector_type(4)));
typedef const __attribute__((address_space(1))) void* gvp;
typedef __attribute__((address_space(3))) void* lvp;

#define S_LEN 4096
#define H_DIM 1024
#define D_DIM 512
#define B_DIM 16
#define OUT_BASE ((size_t)B_DIM * S_LEN * H_DIM)

static __device__ __forceinline__ unsigned short f2bf(float f) {
    union { float f; unsigned int u; } c; c.f = f;
    unsigned int u = c.u;
    return (unsigned short)((u + 0x7FFFu + ((u >> 16) & 1u)) >> 16);
}

// cW1 [K=1024][N=512] f32 -> wT[n][chunk][slot] bf16, pre-swizzled (see R18).
__global__ __launch_bounds__(256) void prep_transpose(const float* __restrict__ cW1,
                                                      unsigned short* __restrict__ wT) {
    __shared__ float tile[64][68];
    const int kt = blockIdx.x >> 3;
    const int nt = blockIdx.x & 7;
    const int tr = threadIdx.x >> 4;
    const int tc = threadIdx.x & 15;
#pragma unroll
    for (int i = 0; i < 4; ++i) {
        const f4 v = *(const f4*)(cW1 + (size_t)(kt * 64 + i * 16 + tr) * D_DIM + nt * 64 + tc * 4);
        tile[i * 16 + tr][tc * 4 + 0] = v.x;
        tile[i * 16 + tr][tc * 4 + 1] = v.y;
        tile[i * 16 + tr][tc * 4 + 2] = v.z;
        tile[i * 16 + tr][tc * 4 + 3] = v.w;
    }
    __syncthreads();
    const int n_local = threadIdx.x & 63;
    const int q = threadIdx.x >> 6;
    const int n = nt * 64 + n_local;
    const int j = q ^ ((n >> 1) & 3);
    char* wTb = (char*)wT;
#pragma unroll
    for (int c_local = 0; c_local < 2; ++c_local) {
        const int k0 = c_local * 32 + j * 8;
        bf8 pk;
#pragma unroll
        for (int i = 0; i < 8; ++i) pk[i] = (short)f2bf(tile[k0 + i][n_local]);
        *(bf8*)(wTb + (size_t)n * 2048 + (kt * 2 + c_local) * 64 + q * 16) = pk;
    }
}

// ============ COMMON GEOMETRY (R18 verbatim) ============
// M=128 (one b, 128 s) x N=256 (D-half), BK=32, 32 chunks, 8 waves (2M x 4N),
// LDS 64 KB (B 3-buf + A dbuf). Role-split nt copy-out; XCD pair-swizzle.
#define GEOM_PREAMBLE                                                                  \
    __shared__ alignas(16) char lds[65536];                                            \
    char* ldsB = lds;                                                                  \
    char* ldsA = lds + 49152;                                                          \
    const int t = threadIdx.x;                                                         \
    const int lane = t & 63;                                                           \
    const int wv = t >> 6;                                                             \
    const int wm = wv >> 2;                                                            \
    const int wn = wv & 3;                                                             \
    const int la = lane & 15;                                                          \
    const int lg = lane >> 4;                                                          \
    const int bid = blockIdx.x;                                                        \
    const int bidL = (bid & 7) * 128 + (bid >> 3);                                     \
    const int b = bidL >> 6;                                                           \
    const int rem = bidL & 63;                                                         \
    const int s0 = (rem >> 1) * 128;                                                   \
    const int nhalf = rem & 1;                                                         \
    const int n0 = nhalf * 256;                                                        \
    const int arow = t >> 2;                                                           \
    const int half = t & 3;                                                            \
    const size_t abase = ((size_t)b * S_LEN + s0 + arow) * H_DIM + half * 4;           \
    const float* srcA = states + abase;                                                \
    float* dstO = out + abase;                                                         \
    const int ax = (arow & 3) ^ ((arow >> 2) & 3);                                     \
    char* dstA0 = ldsA + arow * 64 + (((half >> 1) ^ ax) * 16 + (half & 1) * 8);       \
    char* dstA1 = ldsA + arow * 64 + ((((half >> 1) + 2) ^ ax) * 16 + (half & 1) * 8); \
    const char* srcB = (const char*)wT + (size_t)(n0 + (t >> 2)) * 2048 + (t & 3) * 16;\
    char* dstB = ldsB + t * 16;                                                        \
    const char* brd = ldsB + (wn * 64 + la) * 64 + ((lg ^ ((la >> 1) & 3)) * 16);      \
    const char* ard = ldsA + (wm * 64 + la) * 64 + ((lg ^ (la & 3) ^ ((la >> 2) & 3)) * 16);

#define EPILOGUE_BODY                                                                  \
    float w2v[4], b1v[4];                                                              \
    _Pragma("unroll")                                                                  \
    for (int fc = 0; fc < 4; ++fc) {                                                   \
        const int d = n0 + wn * 64 + fc * 16 + la;                                     \
        w2v[fc] = cW2[d];                                                              \
        b1v[fc] = cb1[d];                                                              \
    }                                                                                  \
    float* part = (float*)ldsA;                                                        \
    _Pragma("unroll")                                                                  \
    for (int fr = 0; fr < 4; ++fr) {                                                   \
        _Pragma("unroll")                                                              \
        for (int rg = 0; rg < 4; ++rg) {                                               \
            float p = 0.f;                                                             \
            _Pragma("unroll")                                                          \
            for (int fc = 0; fc < 4; ++fc)                                             \
                p += fmaxf(acc[fr][fc][rg] + b1v[fc], 0.f) * w2v[fc];                  \
            _Pragma("unroll")                                                          \
            for (int off = 1; off < 16; off <<= 1)                                     \
                p += __shfl_xor(p, off, 64);                                           \
            if (la == 0) part[(wm * 64 + fr * 16 + lg * 4 + rg) * 4 + wn] = p;         \
        }                                                                              \
    }                                                                                  \
    __syncthreads();                                                                   \
    if (t < 128) {                                                                     \
        const float sum = part[t * 4 + 0] + part[t * 4 + 1] + part[t * 4 + 2] + part[t * 4 + 3]; \
        __builtin_nontemporal_store(                                                   \
            sum, part_ws + ((size_t)(nhalf * B_DIM + b)) * S_LEN + s0 + t);            \
    }

#define HELPERS                                                                        \
    auto issueB = [&](int bufi, int ck_) {                                             \
        _Pragma("unroll")                                                              \
        for (int i = 0; i < 2; ++i)                                                    \
            __builtin_amdgcn_global_load_lds((gvp)(srcB + (size_t)i * 128 * 2048 + ck_ * 64), \
                                             (lvp)(dstB + bufi * 16384 + i * 8192), 16, 0, 0); \
    };                                                                                 \
    auto writeA = [&](int bufa, const f4 a0, const f4 a1) {                            \
        bf4 p0, p1;                                                                    \
        p0[0] = (short)f2bf(a0.x); p0[1] = (short)f2bf(a0.y);                          \
        p0[2] = (short)f2bf(a0.z); p0[3] = (short)f2bf(a0.w);                          \
        p1[0] = (short)f2bf(a1.x); p1[1] = (short)f2bf(a1.y);                          \
        p1[2] = (short)f2bf(a1.z); p1[3] = (short)f2bf(a1.w);                          \
        *(bf4*)(dstA0 + bufa * 8192) = p0;                                             \
        *(bf4*)(dstA1 + bufa * 8192) = p1;                                             \
    };                                                                                 \
    auto storeO = [&](int ck_, const f4 a0, const f4 a1) {                             \
        __builtin_nontemporal_store(a0, (f4*)(dstO + ck_ * 32));                       \
        __builtin_nontemporal_store(a1, (f4*)(dstO + ck_ * 32 + 16));                  \
    };

#define BAR() __builtin_amdgcn_sched_barrier(0); __builtin_amdgcn_s_barrier(); __builtin_amdgcn_sched_barrier(0)

// ============ V1: real kernel (R18 verbatim) ============
__global__ __launch_bounds__(512, 4) void comp_gemm_kernel(
    const float* __restrict__ states, const unsigned short* __restrict__ wT,
    const float* __restrict__ cb1, const float* __restrict__ cW2,
    float* __restrict__ out, float* __restrict__ part_ws) {
    GEOM_PREAMBLE
    f4 acc[4][4];
#pragma unroll
    for (int a = 0; a < 4; ++a)
#pragma unroll
        for (int c = 0; c < 4; ++c) acc[a][c] = f4{0.f, 0.f, 0.f, 0.f};
    HELPERS
    f4 qa0 = *(const f4*)(srcA);
    f4 qa1 = *(const f4*)(srcA + 16);
    issueB(0, 0);
    writeA(0, qa0, qa1);
    if (nhalf == 0) storeO(0, qa0, qa1);
    f4 qn0 = *(const f4*)(srcA + 32);
    f4 qn1 = *(const f4*)(srcA + 48);
    issueB(1, 1);
    if (nhalf == 0) { asm volatile("s_waitcnt vmcnt(6) lgkmcnt(0)" ::: "memory"); }
    else            { asm volatile("s_waitcnt vmcnt(4) lgkmcnt(0)" ::: "memory"); }
    BAR();
    qa0 = qn0; qa1 = qn1;
#pragma unroll 1
    for (int ck = 0; ck < 32; ++ck) {
        const int bufc = ck % 3;
        if (ck < 31) {
            if (ck < 30) {
                qn0 = *(const f4*)(srcA + (ck + 2) * 32);
                qn1 = *(const f4*)(srcA + (ck + 2) * 32 + 16);
                issueB((ck + 2) % 3, ck + 2);
            }
            writeA((ck + 1) & 1, qa0, qa1);
            if (((ck + 1) >> 4) == nhalf) storeO(ck + 1, qa0, qa1);
            __builtin_amdgcn_sched_barrier(0);
        }
        bf8 af[4];
#pragma unroll
        for (int fr = 0; fr < 4; ++fr)
            af[fr] = *(const bf8*)(ard + (ck & 1) * 8192 + fr * 1024);
#pragma unroll
        for (int fc = 0; fc < 4; ++fc) {
            const bf8 bv = *(const bf8*)(brd + bufc * 16384 + fc * 1024);
#pragma unroll
            for (int fr = 0; fr < 4; ++fr)
                acc[fr][fc] = __builtin_amdgcn_mfma_f32_16x16x32_bf16(af[fr], bv, acc[fr][fc], 0, 0, 0);
        }
        if (ck < 31) {
            if (ck < 30) {
                const int keep = 4 + ((ck >= 1 && (ck >> 4) == nhalf) ? 2 : 0)
                                   + ((((ck + 1) >> 4) == nhalf) ? 2 : 0);
                if (keep == 8)      { asm volatile("s_waitcnt vmcnt(8) lgkmcnt(0)" ::: "memory"); }
                else if (keep == 6) { asm volatile("s_waitcnt vmcnt(6) lgkmcnt(0)" ::: "memory"); }
                else                { asm volatile("s_waitcnt vmcnt(4) lgkmcnt(0)" ::: "memory"); }
            } else {
                asm volatile("s_waitcnt vmcnt(0) lgkmcnt(0)" ::: "memory");
            }
            BAR();
            if (ck < 30) { qa0 = qn0; qa1 = qn1; }
        }
    }
    EPILOGUE_BODY
}

// ============ V2: no out-stores (cost of the nt write stream) ============
__global__ __launch_bounds__(512, 4) void v2_nostore(
    const float* __restrict__ states, const unsigned short* __restrict__ wT,
    const float* __restrict__ cb1, const float* __restrict__ cW2,
    float* __restrict__ out, float* __restrict__ part_ws) {
    GEOM_PREAMBLE
    (void)dstO;
    f4 acc[4][4];
#pragma unroll
    for (int a = 0; a < 4; ++a)
#pragma unroll
        for (int c = 0; c < 4; ++c) acc[a][c] = f4{0.f, 0.f, 0.f, 0.f};
    HELPERS
    (void)storeO;
    f4 qa0 = *(const f4*)(srcA);
    f4 qa1 = *(const f4*)(srcA + 16);
    issueB(0, 0);
    writeA(0, qa0, qa1);
    f4 qn0 = *(const f4*)(srcA + 32);
    f4 qn1 = *(const f4*)(srcA + 48);
    issueB(1, 1);
    asm volatile("s_waitcnt vmcnt(4) lgkmcnt(0)" ::: "memory");
    BAR();
    qa0 = qn0; qa1 = qn1;
#pragma unroll 1
    for (int ck = 0; ck < 32; ++ck) {
        const int bufc = ck % 3;
        if (ck < 31) {
            if (ck < 30) {
                qn0 = *(const f4*)(srcA + (ck + 2) * 32);
                qn1 = *(const f4*)(srcA + (ck + 2) * 32 + 16);
                issueB((ck + 2) % 3, ck + 2);
            }
            writeA((ck + 1) & 1, qa0, qa1);
            __builtin_amdgcn_sched_barrier(0);
        }
        bf8 af[4];
#pragma unroll
        for (int fr = 0; fr < 4; ++fr)
            af[fr] = *(const bf8*)(ard + (ck & 1) * 8192 + fr * 1024);
#pragma unroll
        for (int fc = 0; fc < 4; ++fc) {
            const bf8 bv = *(const bf8*)(brd + bufc * 16384 + fc * 1024);
#pragma unroll
            for (int fr = 0; fr < 4; ++fr)
                acc[fr][fc] = __builtin_amdgcn_mfma_f32_16x16x32_bf16(af[fr], bv, acc[fr][fc], 0, 0, 0);
        }
        if (ck < 31) {
            if (ck < 30) { asm volatile("s_waitcnt vmcnt(4) lgkmcnt(0)" ::: "memory"); }
            else         { asm volatile("s_waitcnt vmcnt(0) lgkmcnt(0)" ::: "memory"); }
            BAR();
            if (ck < 30) { qa0 = qn0; qa1 = qn1; }
        }
    }
    EPILOGUE_BODY
}

// ============ V3: no MFMA (memory machinery only; frags kept alive) ============
__global__ __launch_bounds__(512, 4) void v3_nomfma(
    const float* __restrict__ states, const unsigned short* __restrict__ wT,
    const float* __restrict__ cb1, const float* __restrict__ cW2,
    float* __restrict__ out, float* __restrict__ part_ws) {
    GEOM_PREAMBLE
    f4 acc[4][4];
#pragma unroll
    for (int a = 0; a < 4; ++a)
#pragma unroll
        for (int c = 0; c < 4; ++c) acc[a][c] = f4{0.f, 0.f, 0.f, 0.f};
    HELPERS
    f4 qa0 = *(const f4*)(srcA);
    f4 qa1 = *(const f4*)(srcA + 16);
    issueB(0, 0);
    writeA(0, qa0, qa1);
    if (nhalf == 0) storeO(0, qa0, qa1);
    f4 qn0 = *(const f4*)(srcA + 32);
    f4 qn1 = *(const f4*)(srcA + 48);
    issueB(1, 1);
    if (nhalf == 0) { asm volatile("s_waitcnt vmcnt(6) lgkmcnt(0)" ::: "memory"); }
    else            { asm volatile("s_waitcnt vmcnt(4) lgkmcnt(0)" ::: "memory"); }
    BAR();
    qa0 = qn0; qa1 = qn1;
#pragma unroll 1
    for (int ck = 0; ck < 32; ++ck) {
        const int bufc = ck % 3;
        if (ck < 31) {
            if (ck < 30) {
                qn0 = *(const f4*)(srcA + (ck + 2) * 32);
                qn1 = *(const f4*)(srcA + (ck + 2) * 32 + 16);
                issueB((ck + 2) % 3, ck + 2);
            }
            writeA((ck + 1) & 1, qa0, qa1);
            if (((ck + 1) >> 4) == nhalf) storeO(ck + 1, qa0, qa1);
            __builtin_amdgcn_sched_barrier(0);
        }
        bf8 af[4];
#pragma unroll
        for (int fr = 0; fr < 4; ++fr) {
            af[fr] = *(const bf8*)(ard + (ck & 1) * 8192 + fr * 1024);
            asm volatile("" :: "v"(af[fr]));      // keep-alive (rule #17)
        }
#pragma unroll
        for (int fc = 0; fc < 4; ++fc) {
            const bf8 bv = *(const bf8*)(brd + bufc * 16384 + fc * 1024);
            asm volatile("" :: "v"(bv));          // keep-alive
        }
        if (ck < 31) {
            if (ck < 30) {
                const int keep = 4 + ((ck >= 1 && (ck >> 4) == nhalf) ? 2 : 0)
                                   + ((((ck + 1) >> 4) == nhalf) ? 2 : 0);
                if (keep == 8)      { asm volatile("s_waitcnt vmcnt(8) lgkmcnt(0)" ::: "memory"); }
                else if (keep == 6) { asm volatile("s_waitcnt vmcnt(6) lgkmcnt(0)" ::: "memory"); }
                else                { asm volatile("s_waitcnt vmcnt(4) lgkmcnt(0)" ::: "memory"); }
            } else {
                asm volatile("s_waitcnt vmcnt(0) lgkmcnt(0)" ::: "memory");
            }
            BAR();
            if (ck < 30) { qa0 = qn0; qa1 = qn1; }
        }
    }
    EPILOGUE_BODY
}

// ============ V4: A-stream + stores only (no B, no MFMA) ============
__global__ __launch_bounds__(512, 4) void v4_astream(
    const float* __restrict__ states, const unsigned short* __restrict__ wT,
    const float* __restrict__ cb1, const float* __restrict__ cW2,
    float* __restrict__ out, float* __restrict__ part_ws) {
    GEOM_PREAMBLE
    (void)srcB; (void)dstB; (void)brd; (void)ard;
    f4 acc[4][4];
#pragma unroll
    for (int a = 0; a < 4; ++a)
#pragma unroll
        for (int c = 0; c < 4; ++c) acc[a][c] = f4{0.f, 0.f, 0.f, 0.f};
    HELPERS
    (void)issueB;
    f4 qa0 = *(const f4*)(srcA);
    f4 qa1 = *(const f4*)(srcA + 16);
    writeA(0, qa0, qa1);
    if (nhalf == 0) storeO(0, qa0, qa1);
    f4 qn0 = *(const f4*)(srcA + 32);
    f4 qn1 = *(const f4*)(srcA + 48);
    asm volatile("s_waitcnt lgkmcnt(0)" ::: "memory");
    BAR();
    qa0 = qn0; qa1 = qn1;
#pragma unroll 1
    for (int ck = 0; ck < 32; ++ck) {
        if (ck < 31) {
            if (ck < 30) {
                qn0 = *(const f4*)(srcA + (ck + 2) * 32);
                qn1 = *(const f4*)(srcA + (ck + 2) * 32 + 16);
            }
            writeA((ck + 1) & 1, qa0, qa1);
            if (((ck + 1) >> 4) == nhalf) storeO(ck + 1, qa0, qa1);
            __builtin_amdgcn_sched_barrier(0);
        }
        if (ck < 31) {
            if (ck < 30) { asm volatile("s_waitcnt vmcnt(4) lgkmcnt(0)" ::: "memory"); }
            else         { asm volatile("s_waitcnt vmcnt(0) lgkmcnt(0)" ::: "memory"); }
            BAR();
            if (ck < 30) { qa0 = qn0; qa1 = qn1; }
        }
    }
    EPILOGUE_BODY
}

// ============ V5: B-pipeline + MFMA only (no A stream) ============
__global__ __launch_bounds__(512, 4) void v5_bmfma(
    const float* __restrict__ states, const unsigned short* __restrict__ wT,
    const float* __restrict__ cb1, const float* __restrict__ cW2,
    float* __restrict__ out, float* __restrict__ part_ws) {
    GEOM_PREAMBLE
    (void)srcA; (void)dstO; (void)dstA0; (void)dstA1;
    f4 acc[4][4];
#pragma unroll
    for (int a = 0; a < 4; ++a)
#pragma unroll
        for (int c = 0; c < 4; ++c) acc[a][c] = f4{0.f, 0.f, 0.f, 0.f};
    HELPERS
    (void)writeA; (void)storeO;
    issueB(0, 0);
    issueB(1, 1);
    asm volatile("s_waitcnt vmcnt(2) lgkmcnt(0)" ::: "memory");
    BAR();
#pragma unroll 1
    for (int ck = 0; ck < 32; ++ck) {
        const int bufc = ck % 3;
        if (ck < 30) {
            issueB((ck + 2) % 3, ck + 2);
            __builtin_amdgcn_sched_barrier(0);
        }
        bf8 af[4];
#pragma unroll
        for (int fr = 0; fr < 4; ++fr)
            af[fr] = *(const bf8*)(ard + (ck & 1) * 8192 + fr * 1024);  // junk A, same traffic
#pragma unroll
        for (int fc = 0; fc < 4; ++fc) {
            const bf8 bv = *(const bf8*)(brd + bufc * 16384 + fc * 1024);
#pragma unroll
            for (int fr = 0; fr < 4; ++fr)
                acc[fr][fc] = __builtin_amdgcn_mfma_f32_16x16x32_bf16(af[fr], bv, acc[fr][fc], 0, 0, 0);
        }
        if (ck < 31) {
            if (ck < 30) { asm volatile("s_waitcnt vmcnt(2) lgkmcnt(0)" ::: "memory"); }
            else         { asm volatile("s_waitcnt vmcnt(0) lgkmcnt(0)" ::: "memory"); }
            BAR();
        }
    }
    EPILOGUE_BODY
}

// comp_mean / steps / rb constants (runs BEFORE the ablation variants so their
// part_ws scribbles are dead writes).
__global__ __launch_bounds__(256) void reduce_comp(const float* __restrict__ part_ws,
                                                   const float* __restrict__ cb2,
                                                   float* __restrict__ out) {
    const int s = blockIdx.x * 256 + threadIdx.x;
    const float c2 = cb2[0];
    float sum = 0.f;
#pragma unroll
    for (int b = 0; b < B_DIM; ++b) {
        const float l = c2 + part_ws[(size_t)b * S_LEN + s]
                           + part_ws[((size_t)B_DIM + b) * S_LEN + s];
        sum += 1.f / (1.f + __expf(-l));
    }
    out[OUT_BASE + S_LEN + s] = sum * (1.f / 16.f);
    out[OUT_BASE + s] = 1.0f;
    if (s == 0) out[OUT_BASE + 2 * S_LEN] = -3968.0f;
}

extern "C" void kernel_launch(void* const* d_in, const int* in_sizes, int n_in,
                              void* d_out, int out_size, void* d_ws, size_t ws_size,
                              hipStream_t stream) {
    const float* states = (const float*)d_in[0];
    const float* cW1 = (const float*)d_in[5];
    const float* cb1 = (const float*)d_in[6];
    const float* cW2 = (const float*)d_in[7];
    const float* cb2 = (const float*)d_in[8];
    float* out = (float*)d_out;
    unsigned short* wT = (unsigned short*)d_ws;
    float* part_ws = (float*)((char*)d_ws + (size_t)D_DIM * H_DIM * 2);

    hipLaunchKernelGGL(prep_transpose, dim3(128), dim3(256), 0, stream, cW1, wT);
    hipLaunchKernelGGL(comp_gemm_kernel, dim3(1024), dim3(512), 0, stream,
                       states, wT, cb1, cW2, out, part_ws);
    hipLaunchKernelGGL(reduce_comp, dim3(16), dim3(256), 0, stream, part_ws, cb2, out);
    // ---- ablation probes: write only to part_ws (dead after reduce_comp) ----
    hipLaunchKernelGGL(v2_nostore, dim3(1024), dim3(512), 0, stream,
                       states, wT, cb1, cW2, out, part_ws);
    hipLaunchKernelGGL(v3_nomfma, dim3(1024), dim3(512), 0, stream,
                       states, wT, cb1, cW2, out, part_ws);
    hipLaunchKernelGGL(v4_astream, dim3(1024), dim3(512), 0, stream,
                       states, wT, cb1, cW2, out, part_ws);
    hipLaunchKernelGGL(v5_bmfma, dim3(1024), dim3(512), 0, stream,
                       states, wT, cb1, cW2, out, part_ws);
}

// Round 21
// 409.939 us; speedup vs baseline: 1.2863x; 1.2863x over previous
//
#include <hip/hip_runtime.h>
#include <hip/hip_bf16.h>

typedef short bf8 __attribute__((ext_vector_type(8)));   // 8 bf16 (4 VGPRs)
typedef float f4 __attribute__((ext_vector_type(4)));
typedef const __attribute__((address_space(1))) void* gvp;
typedef __attribute__((address_space(3))) void* lvp;

#define S_LEN 4096
#define H_DIM 1024
#define D_DIM 512
#define B_DIM 16
#define OUT_BASE ((size_t)B_DIM * S_LEN * H_DIM)
#define M_TOTAL ((size_t)B_DIM * S_LEN)   // 65536 flat rows (b*4096+s)

// float -> bf16 bits, round-to-nearest-even
static __device__ __forceinline__ unsigned short f2bf(float f) {
    union { float f; unsigned int u; } c; c.f = f;
    unsigned int u = c.u;
    return (unsigned short)((u + 0x7FFFu + ((u >> 16) & 1u)) >> 16);
}

// cW1 [K=1024][N=512] f32 -> wT[n][chunk 0..31][slot 0..3] bf16 (pitch 2048 B),
// PRE-SWIZZLED: slot sl holds k-slot j = sl ^ ((n>>1)&3); GEMM's linear global_load_lds
// + swizzled ds_read (slot = lg ^ ((la>>1)&3)) recovers k-slot lg (2-way bank, free).
__global__ __launch_bounds__(256) void prep_transpose(const float* __restrict__ cW1,
                                                      unsigned short* __restrict__ wT) {
    __shared__ float tile[64][68];
    const int kt = blockIdx.x >> 3;
    const int nt = blockIdx.x & 7;
    const int tr = threadIdx.x >> 4;
    const int tc = threadIdx.x & 15;
#pragma unroll
    for (int i = 0; i < 4; ++i) {
        const f4 v = *(const f4*)(cW1 + (size_t)(kt * 64 + i * 16 + tr) * D_DIM + nt * 64 + tc * 4);
        tile[i * 16 + tr][tc * 4 + 0] = v.x;
        tile[i * 16 + tr][tc * 4 + 1] = v.y;
        tile[i * 16 + tr][tc * 4 + 2] = v.z;
        tile[i * 16 + tr][tc * 4 + 3] = v.w;
    }
    __syncthreads();
    const int n_local = threadIdx.x & 63;
    const int q = threadIdx.x >> 6;        // slot 0..3
    const int n = nt * 64 + n_local;
    const int j = q ^ ((n >> 1) & 3);      // data k-slot stored at slot q
    char* wTb = (char*)wT;
#pragma unroll
    for (int c_local = 0; c_local < 2; ++c_local) {
        const int k0 = c_local * 32 + j * 8;
        bf8 pk;
#pragma unroll
        for (int i = 0; i < 8; ++i) pk[i] = (short)f2bf(tile[k0 + i][n_local]);
        *(bf8*)(wTb + (size_t)n * 2048 + (kt * 2 + c_local) * 64 + q * 16) = pk;
    }
}

// Mixed-block kernel: bid%3==2 -> streaming copy block (dense, nt); else GEMM block.
// GEMM: WAVE-AUTONOMOUS, ZERO barriers in the K-loop. Block = 8 independent waves;
// wave w owns M=64 rows (flat stripe gm*512 + w*64) x N=64 (slice gn), K=1024 in 32
// chunks of 32. Per wave: private 8 KB LDS dbuf for its B slice (global_load_lds,
// per-wave vmcnt -> a stall never convoys other waves); A fragments loaded per-lane
// DIRECT from global (lane(la,lg), row fr*16+la, 32 B = exactly its MFMA A-fragment,
// R9-validated); one self-sufficient vmcnt(4) fence per iter (retires B(ck)+qa,
// keeps B(ck+1) in flight). Epilogue: no LDS, no syncthreads — per-slice partials.
__global__ __launch_bounds__(512, 4) void fused_kernel(
    const float* __restrict__ states,
    const unsigned short* __restrict__ wT,
    const float* __restrict__ cb1,
    const float* __restrict__ cW2,
    float* __restrict__ out,
    float* __restrict__ part_ws) {
    __shared__ alignas(16) char lds[65536];   // 8 waves x [2][64 rows][64 B]

    const int t = threadIdx.x;
    const int r3 = blockIdx.x % 3;
    const int g3 = blockIdx.x / 3;

    if (r3 == 2) {
        // ---- copy block: contiguous 512 KB slab, dense f4 reads / nt f4 stores ----
        const size_t off = (size_t)g3 * 131072 + t * 4;
        const float* sp = states + off;
        float* op = out + off;
#pragma unroll 1
        for (int o = 0; o < 8; ++o) {
            f4 v[8];
#pragma unroll
            for (int j = 0; j < 8; ++j)
                v[j] = *(const f4*)(sp + (size_t)(o * 8 + j) * 2048);
#pragma unroll
            for (int j = 0; j < 8; ++j)
                __builtin_nontemporal_store(v[j], (f4*)(op + (size_t)(o * 8 + j) * 2048));
        }
        return;
    }

    // ---- GEMM block ----
    const int gid = g3 * 2 + r3;          // 0..1023
    const int gm = gid >> 3;              // 0..127 : M stripe of 512 flat rows
    const int gn = gid & 7;               // 0..7   : N slice of 64
    const int n0 = gn * 64;
    const int lane = t & 63;
    const int w = t >> 6;                 // wave 0..7
    const int la = lane & 15;
    const int lg = lane >> 4;
    const size_t mbase = (size_t)gm * 512 + w * 64;   // wave's first flat row

    // A per-lane: row (mbase + fr*16 + la), floats [ck*32 + lg*8, +8)
    const float* aptr = states + (mbase + la) * (size_t)H_DIM + lg * 8;

    // B staging (per-wave private): rows n0..n0+63, 4 KB/chunk, dbuf
    char* myB = lds + w * 8192;
    const char* bsrc = (const char*)wT + (size_t)(n0 + (lane >> 2)) * 2048 + (lane & 3) * 16;
    char* bdst = myB + lane * 16;
    const char* brd = myB + la * 64 + ((lg ^ ((la >> 1) & 3)) * 16);

    f4 acc[4][4];
#pragma unroll
    for (int a = 0; a < 4; ++a)
#pragma unroll
        for (int c = 0; c < 4; ++c) acc[a][c] = f4{0.f, 0.f, 0.f, 0.f};

    auto issueB = [&](int buf, int ck) {
#pragma unroll
        for (int i = 0; i < 4; ++i)
            __builtin_amdgcn_global_load_lds((gvp)(bsrc + (size_t)i * 16 * 2048 + ck * 64),
                                             (lvp)(bdst + buf * 4096 + i * 1024), 16, 0, 0);
    };

    issueB(0, 0);   // B(0) -> buf0; retired by iter0's vmcnt(4) fence

#pragma unroll 2
    for (int ck = 0; ck < 32; ++ck) {
        const int buf = ck & 1;
        // A(ck): 8 f4 per lane (4 fr rows x 32 B)
        f4 qa[4][2];
#pragma unroll
        for (int fr = 0; fr < 4; ++fr) {
            qa[fr][0] = *(const f4*)(aptr + (size_t)fr * 16 * H_DIM + ck * 32);
            qa[fr][1] = *(const f4*)(aptr + (size_t)fr * 16 * H_DIM + ck * 32 + 4);
        }
        if (ck < 31) issueB(buf ^ 1, ck + 1);   // B(ck+1), younger than qa
        // cvt A -> fragments (compiler auto-waits qa; in-order retire also covers B(ck))
        bf8 af[4];
#pragma unroll
        for (int fr = 0; fr < 4; ++fr) {
            af[fr][0] = (short)f2bf(qa[fr][0].x); af[fr][1] = (short)f2bf(qa[fr][0].y);
            af[fr][2] = (short)f2bf(qa[fr][0].z); af[fr][3] = (short)f2bf(qa[fr][0].w);
            af[fr][4] = (short)f2bf(qa[fr][1].x); af[fr][5] = (short)f2bf(qa[fr][1].y);
            af[fr][6] = (short)f2bf(qa[fr][1].z); af[fr][7] = (short)f2bf(qa[fr][1].w);
        }
        // Self-sufficient fence: <=4 outstanding == only B(ck+1) still flying;
        // B(ck) + qa provably retired. Per-wave wait -> no cross-wave convoy.
        asm volatile("s_waitcnt vmcnt(4)" ::: "memory");
        __builtin_amdgcn_sched_barrier(0);
#pragma unroll
        for (int fc = 0; fc < 4; ++fc) {
            const bf8 bv = *(const bf8*)(brd + buf * 4096 + fc * 16 * 64);
#pragma unroll
            for (int fr = 0; fr < 4; ++fr)
                acc[fr][fc] = __builtin_amdgcn_mfma_f32_16x16x32_bf16(af[fr], bv, acc[fr][fc], 0, 0, 0);
        }
    }

    // ---- epilogue (wave-local, no LDS): relu + dot(cW2 slice) -> per-slice partial ----
    float w2v[4], b1v[4];
#pragma unroll
    for (int fc = 0; fc < 4; ++fc) {
        const int d = n0 + fc * 16 + la;
        w2v[fc] = cW2[d];
        b1v[fc] = cb1[d];
    }
#pragma unroll
    for (int fr = 0; fr < 4; ++fr) {
#pragma unroll
        for (int rg = 0; rg < 4; ++rg) {
            float p = 0.f;
#pragma unroll
            for (int fc = 0; fc < 4; ++fc)
                p += fmaxf(acc[fr][fc][rg] + b1v[fc], 0.f) * w2v[fc];
#pragma unroll
            for (int off = 1; off < 16; off <<= 1)
                p += __shfl_xor(p, off, 64);      // sum over 16 lane-columns (n)
            if (la == 0) {
                const size_t m = mbase + fr * 16 + lg * 4 + rg;   // C row = lg*4+rg
                __builtin_nontemporal_store(p, part_ws + (size_t)gn * M_TOTAL + m);
            }
        }
    }
}

// comp_mean[s] = (1/16) sum_b sigmoid(cb2 + sum_{gn<8} part[gn][b*4096+s]);
// steps_used ≡ 1 (rb<=128-t can never make trunc(rb/(S-t+1))>=2; negative rb clips
// to 1); rb_final = 128-4096 = -3968.
__global__ __launch_bounds__(256) void reduce_comp(const float* __restrict__ part_ws,
                                                   const float* __restrict__ cb2,
                                                   float* __restrict__ out) {
    const int s = blockIdx.x * 256 + threadIdx.x;
    const float c2 = cb2[0];
    float sum = 0.f;
#pragma unroll
    for (int b = 0; b < B_DIM; ++b) {
        float l = c2;
#pragma unroll
        for (int gn = 0; gn < 8; ++gn)
            l += part_ws[(size_t)gn * M_TOTAL + (size_t)b * S_LEN + s];
        sum += 1.f / (1.f + __expf(-l));
    }
    out[OUT_BASE + S_LEN + s] = sum * (1.f / 16.f);   // comp_mean
    out[OUT_BASE + s] = 1.0f;                          // steps_used
    if (s == 0) out[OUT_BASE + 2 * S_LEN] = -3968.0f;  // rb_final.mean()
}

extern "C" void kernel_launch(void* const* d_in, const int* in_sizes, int n_in,
                              void* d_out, int out_size, void* d_ws, size_t ws_size,
                              hipStream_t stream) {
    const float* states = (const float*)d_in[0];
    const float* cW1 = (const float*)d_in[5];
    const float* cb1 = (const float*)d_in[6];
    const float* cW2 = (const float*)d_in[7];
    const float* cb2 = (const float*)d_in[8];
    float* out = (float*)d_out;
    unsigned short* wT = (unsigned short*)d_ws;                        // 1 MB bf16, pre-swizzled
    float* part_ws = (float*)((char*)d_ws + (((size_t)1) << 20));      // 2 MB [8][65536]

    hipLaunchKernelGGL(prep_transpose, dim3(128), dim3(256), 0, stream, cW1, wT);
    hipLaunchKernelGGL(fused_kernel, dim3(1536), dim3(512), 0, stream,
                       states, wT, cb1, cW2, out, part_ws);
    hipLaunchKernelGGL(reduce_comp, dim3(16), dim3(256), 0, stream, part_ws, cb2, out);
}

// Round 22
// 165.721 us; speedup vs baseline: 3.1818x; 2.4737x over previous
//
#include <hip/hip_runtime.h>
#include <hip/hip_bf16.h>

typedef short bf8 __attribute__((ext_vector_type(8)));   // 8 bf16 (4 VGPRs)
typedef short bf4 __attribute__((ext_vector_type(4)));   // 4 bf16 (8 B)
typedef float f4 __attribute__((ext_vector_type(4)));
typedef const __attribute__((address_space(1))) void* gvp;
typedef __attribute__((address_space(3))) void* lvp;

#define S_LEN 4096
#define H_DIM 1024
#define D_DIM 512
#define B_DIM 16
#define OUT_BASE ((size_t)B_DIM * S_LEN * H_DIM)

// float -> bf16 bits, round-to-nearest-even
static __device__ __forceinline__ unsigned short f2bf(float f) {
    union { float f; unsigned int u; } c; c.f = f;
    unsigned int u = c.u;
    return (unsigned short)((u + 0x7FFFu + ((u >> 16) & 1u)) >> 16);
}

// cW1 [K=1024][N=512] f32 -> wT[n][chunk 0..31][slot 0..3] bf16 (pitch 2048 B),
// PRE-SWIZZLED: slot sl holds k-slot j = sl ^ ((n>>1)&3). GEMM's linear global_load_lds
// + swizzled ds_read (slot = lg ^ ((la>>1)&3)) recovers k-slot lg; 2-way-bank (free).
__global__ __launch_bounds__(256) void prep_transpose(const float* __restrict__ cW1,
                                                      unsigned short* __restrict__ wT) {
    __shared__ float tile[64][68];
    const int kt = blockIdx.x >> 3;
    const int nt = blockIdx.x & 7;
    const int tr = threadIdx.x >> 4;
    const int tc = threadIdx.x & 15;
#pragma unroll
    for (int i = 0; i < 4; ++i) {
        const f4 v = *(const f4*)(cW1 + (size_t)(kt * 64 + i * 16 + tr) * D_DIM + nt * 64 + tc * 4);
        tile[i * 16 + tr][tc * 4 + 0] = v.x;
        tile[i * 16 + tr][tc * 4 + 1] = v.y;
        tile[i * 16 + tr][tc * 4 + 2] = v.z;
        tile[i * 16 + tr][tc * 4 + 3] = v.w;
    }
    __syncthreads();
    const int n_local = threadIdx.x & 63;
    const int q = threadIdx.x >> 6;        // slot 0..3
    const int n = nt * 64 + n_local;
    const int j = q ^ ((n >> 1) & 3);      // data k-slot stored at slot q
    char* wTb = (char*)wT;
#pragma unroll
    for (int c_local = 0; c_local < 2; ++c_local) {
        const int k0 = c_local * 32 + j * 8;
        bf8 pk;
#pragma unroll
        for (int i = 0; i < 8; ++i) pk[i] = (short)f2bf(tile[k0 + i][n_local]);
        *(bf8*)(wTb + (size_t)n * 2048 + (kt * 2 + c_local) * 64 + q * 16) = pk;
    }
}

// Fused stream+GEMM, FULL N=512 (no A duplication) + store-last counted schedule +
// 2 gangs/CU. M=64 (one b, 64 s) x N=512, BK=32, 32 chunks, 8 waves (2M x 4N),
// wave tile 32x128, acc[2][8]=64 AGPR + ~55 VGPR <= 128 -> 4 waves/SIMD; LDS 72 KB
// (B dbuf 64 + A dbuf 8) -> 2 blocks/CU. Per period (issue order): B(ck+1) x4,
// glA(ck+2), writeA(ck+1) [qa-wait retires only glA(ck+1)], storeO(ck+1) LAST
// (youngest). Tail vmcnt(2): retires [st(ck), B(ck+1)x4], keeps [glA(ck+2),
// st(ck+1)] -> stores 1.5 periods slack, A 2 periods, B (L2) covered. Block
// produces FINAL per-(b,s) sigmoid/16 (full N) -> simple reduce over b.
__global__ __launch_bounds__(512, 4) void comp_gemm_kernel(
    const float* __restrict__ states,
    const unsigned short* __restrict__ wT,
    const float* __restrict__ cb1,
    const float* __restrict__ cW2,
    const float* __restrict__ cb2,
    float* __restrict__ out,
    float* __restrict__ part_ws) {
    __shared__ alignas(16) char lds[73728];   // B [2][512][64] @0 ; A [2][64][64] @65536
    char* ldsB = lds;
    char* ldsA = lds + 65536;

    const int t = threadIdx.x;
    const int lane = t & 63;
    const int wv = t >> 6;                // 0..7
    const int wm = wv >> 2;               // 0..1 : rows [wm*32, +32)
    const int wn = wv & 3;                // 0..3 : cols [wn*128, +128)
    const int la = lane & 15;
    const int lg = lane >> 4;
    const int b = blockIdx.x >> 6;        // 16 b
    const int s0 = (blockIdx.x & 63) * 64;

    // ---- A staging / fused copy-out: (row = t>>3, kq = t&7), one f4 = 16 B/thread;
    // threads t..t+7 cover 128 B contiguous of one row -> per-instruction DENSE ----
    const int arow = t >> 3;
    const int kq = t & 7;
    const size_t abase = ((size_t)b * S_LEN + s0 + arow) * H_DIM + kq * 4;
    const float* srcA = states + abase;
    float* dstO = out + abase;
    const int ax = (arow & 3) ^ ((arow >> 2) & 3);
    char* dstA = ldsA + arow * 64 + ((((kq >> 1) ^ ax) & 3) * 16 + (kq & 1) * 8);

    // ---- B staging: 4 x global_load_lds(16B/lane)/chunk; linear dest, swizzled src ----
    const char* srcB = (const char*)wT + (size_t)(t >> 2) * 2048 + (t & 3) * 16;
    char* dstB = ldsB + t * 16;

    // ---- fragment read bases (2-way bank, free) ----
    const char* brd = ldsB + (wn * 128 + la) * 64 + ((lg ^ ((la >> 1) & 3)) * 16);
    const char* ard = ldsA + (wm * 32 + la) * 64 + ((lg ^ (la & 3) ^ ((la >> 2) & 3)) * 16);

    f4 acc[2][8];
#pragma unroll
    for (int a = 0; a < 2; ++a)
#pragma unroll
        for (int c = 0; c < 8; ++c) acc[a][c] = f4{0.f, 0.f, 0.f, 0.f};

    auto issueB = [&](int bufi, int ck_) {
#pragma unroll
        for (int i = 0; i < 4; ++i)
            __builtin_amdgcn_global_load_lds((gvp)(srcB + (size_t)i * 128 * 2048 + ck_ * 64),
                                             (lvp)(dstB + bufi * 32768 + i * 8192), 16, 0, 0);
    };
    auto writeA = [&](int bufa, const f4 a) {
        bf4 p;
        p[0] = (short)f2bf(a.x); p[1] = (short)f2bf(a.y);
        p[2] = (short)f2bf(a.z); p[3] = (short)f2bf(a.w);
        *(bf4*)(dstA + bufa * 4096) = p;
    };
    auto storeO = [&](int ck_, const f4 a) {   // nt, per-instruction dense
        __builtin_nontemporal_store(a, (f4*)(dstO + ck_ * 32));
    };

    // ---- prologue: [glA0, B0 x4, writeA0 (retires glA0), glA1, st0] ----
    f4 qa = *(const f4*)(srcA);
    issueB(0, 0);
    writeA(0, qa);                        // implicit wait retires glA0 only (B0 younger)
    f4 qn = *(const f4*)(srcA + 32);      // glA(1)
    storeO(0, qa);                        // st(0) youngest
    // queue: [B0 x4, glA1, st0] -> vmcnt(2) retires B0, keeps [glA1, st0]
    asm volatile("s_waitcnt vmcnt(2) lgkmcnt(0)" ::: "memory");
    __builtin_amdgcn_sched_barrier(0);
    __builtin_amdgcn_s_barrier();
    __builtin_amdgcn_sched_barrier(0);
    qa = qn;

#pragma unroll 1
    for (int ck = 0; ck < 32; ++ck) {
        const int buf = ck & 1;
        if (ck < 31) {
            issueB(buf ^ 1, ck + 1);                      // B(ck+1) x4
            if (ck < 30) qn = *(const f4*)(srcA + (ck + 2) * 32);   // glA(ck+2)
            writeA(buf ^ 1, qa);          // qa-wait retires only glA(ck+1) (oldest)
            storeO(ck + 1, qa);           // st(ck+1) youngest
            __builtin_amdgcn_sched_barrier(0);
        }
        // ---- compute chunk ck: A from ldsA[buf], B from ldsB[buf] ----
        bf8 af[2];
#pragma unroll
        for (int fr = 0; fr < 2; ++fr)
            af[fr] = *(const bf8*)(ard + buf * 4096 + fr * 1024);
#pragma unroll
        for (int fc = 0; fc < 8; ++fc) {
            const bf8 bv = *(const bf8*)(brd + buf * 32768 + fc * 1024);
#pragma unroll
            for (int fr = 0; fr < 2; ++fr)
                acc[fr][fc] = __builtin_amdgcn_mfma_f32_16x16x32_bf16(af[fr], bv, acc[fr][fc], 0, 0, 0);
        }
        if (ck < 31) {
            // tail: retire [st(ck), B(ck+1) x4]; keep [glA(ck+2), st(ck+1)] -> vmcnt(2)
            // (ck==30: no glA(32) -> keep [st(31)] -> vmcnt(1))
            if (ck < 30) { asm volatile("s_waitcnt vmcnt(2) lgkmcnt(0)" ::: "memory"); }
            else         { asm volatile("s_waitcnt vmcnt(1) lgkmcnt(0)" ::: "memory"); }
            __builtin_amdgcn_sched_barrier(0);
            __builtin_amdgcn_s_barrier();
            __builtin_amdgcn_sched_barrier(0);
            if (ck < 30) qa = qn;
        }
    }

    // ---- epilogue: relu + dot(cW2) over FULL N=512 -> final sigmoid/16 per (b,s) ----
    float w2v[8], b1v[8];
#pragma unroll
    for (int fc = 0; fc < 8; ++fc) {
        const int d = wn * 128 + fc * 16 + la;
        w2v[fc] = cW2[d];
        b1v[fc] = cb1[d];
    }
    __syncthreads();                      // done reading ldsA -> overlay scratch
    float* part = (float*)ldsA;           // [64 rows][4 wn]
#pragma unroll
    for (int fr = 0; fr < 2; ++fr) {
#pragma unroll
        for (int rg = 0; rg < 4; ++rg) {
            float p = 0.f;
#pragma unroll
            for (int fc = 0; fc < 8; ++fc)
                p += fmaxf(acc[fr][fc][rg] + b1v[fc], 0.f) * w2v[fc];
#pragma unroll
            for (int off = 1; off < 16; off <<= 1)
                p += __shfl_xor(p, off, 64);      // sum over 16 lane-columns (n)
            if (la == 0) part[(wm * 32 + fr * 16 + lg * 4 + rg) * 4 + wn] = p;
        }
    }
    __syncthreads();
    if (t < 64) {
        const float sum = cb2[0] + part[t * 4 + 0] + part[t * 4 + 1]
                                 + part[t * 4 + 2] + part[t * 4 + 3];
        const float sg = 1.f / (1.f + __expf(-sum));
        __builtin_nontemporal_store(sg * (1.f / 16.f), part_ws + (size_t)b * S_LEN + s0 + t);
    }
}

// comp_mean[s] = sum_b partial[b][s]; steps_used ≡ 1 (rb<=128-t can never make
// trunc(rb/(S-t+1))>=2; negative rb clips to 1); rb_final = 128-4096 = -3968.
__global__ __launch_bounds__(256) void reduce_comp(const float* __restrict__ part_ws,
                                                   float* __restrict__ out) {
    const int s = blockIdx.x * 256 + threadIdx.x;
    float sum = 0.f;
#pragma unroll
    for (int b = 0; b < B_DIM; ++b) sum += part_ws[(size_t)b * S_LEN + s];
    out[OUT_BASE + S_LEN + s] = sum;     // comp_mean
    out[OUT_BASE + s] = 1.0f;            // steps_used
    if (s == 0) out[OUT_BASE + 2 * S_LEN] = -3968.0f;
}

extern "C" void kernel_launch(void* const* d_in, const int* in_sizes, int n_in,
                              void* d_out, int out_size, void* d_ws, size_t ws_size,
                              hipStream_t stream) {
    const float* states = (const float*)d_in[0];
    const float* cW1 = (const float*)d_in[5];
    const float* cb1 = (const float*)d_in[6];
    const float* cW2 = (const float*)d_in[7];
    const float* cb2 = (const float*)d_in[8];
    float* out = (float*)d_out;
    unsigned short* wT = (unsigned short*)d_ws;                        // 1 MB bf16, pre-swizzled
    float* part_ws = (float*)((char*)d_ws + (((size_t)1) << 20));      // 256 KB [16][4096]

    hipLaunchKernelGGL(prep_transpose, dim3(128), dim3(256), 0, stream, cW1, wT);
    hipLaunchKernelGGL(comp_gemm_kernel, dim3(1024), dim3(512), 0, stream,
                       states, wT, cb1, cW2, cb2, out, part_ws);
    hipLaunchKernelGGL(reduce_comp, dim3(16), dim3(256), 0, stream, part_ws, out);
}